// Round 12
// baseline (86.305 us; speedup 1.0000x reference)
//
#include <hip/hip_runtime.h>
#include <hip/hip_bf16.h>

// Problem constants
#define B_   4
#define L_   2048
#define D_   256
#define NC   128
#define CL   16
#define NBLK (B_*NC)   // 512 chunks
#define ANG  0.02454369260617025967f   // 2*pi/256

typedef __bf16 bf16x8 __attribute__((ext_vector_type(8)));
typedef __bf16 bf16x4 __attribute__((ext_vector_type(4)));
typedef float  f32x4  __attribute__((ext_vector_type(4)));

// ===== kernel 1: LN + proj(MFMA, inline W-frags) + delta + local scan =====
__global__ __launch_bounds__(256) void k_lnscan(
        const float* __restrict__ x, const float* __restrict__ ln_g, const float* __restrict__ ln_b,
        const float* __restrict__ W_xproj, const float* __restrict__ W_dt,
        const float* __restrict__ b_dt, const float* __restrict__ A_log,
        unsigned int* __restrict__ dxn,
        float* __restrict__ Bc_o, float* __restrict__ Cc_o,
        float* __restrict__ dsum_o, float* __restrict__ S)
{
    __shared__ __align__(16) float xn_s[16 * 260];   // stride 260 -> conflict-free
    __shared__ __align__(16) __bf16 xnb[16 * 256];   // bf16 A-tile [m][d], XOR-swizzled
    __shared__ float dbc_s[16 * 52];
    int tid = threadIdx.x, wave = tid >> 6, lane = tid & 63;
    int blk = blockIdx.x;
    int grow0 = blk * CL;
    char* xnb_c = (char*)xnb;

    // --- Phase A: LayerNorm, 4 rows per wave ---
#pragma unroll
    for (int rr = 0; rr < 4; rr++) {
        int r = wave * 4 + rr;
        const float* xr = x + (size_t)(grow0 + r) * D_;
        float v[4];
#pragma unroll
        for (int q = 0; q < 4; q++) v[q] = xr[lane + q * 64];
        float sum = v[0] + v[1] + v[2] + v[3];
        float sq  = v[0]*v[0] + v[1]*v[1] + v[2]*v[2] + v[3]*v[3];
#pragma unroll
        for (int off = 32; off; off >>= 1) { sum += __shfl_xor(sum, off); sq += __shfl_xor(sq, off); }
        float mu = sum * (1.f / D_);
        float rstd = rsqrtf(sq * (1.f / D_) - mu * mu + 1e-5f);
#pragma unroll
        for (int q = 0; q < 4; q++) {
            int d = lane + q * 64;
            float xv = (v[q] - mu) * rstd * ln_g[d] + ln_b[d];
            xn_s[r * 260 + d] = xv;
            *(__bf16*)(xnb_c + r * 512 + ((d * 2) ^ ((r & 7) << 4))) = (__bf16)xv;
        }
    }
    __syncthreads();

    // --- Phase B: dbc = xn @ W_xproj^T via MFMA; W-frags inlined ---
    if (wave < 3) {
        int jcol = wave * 16 + (lane & 15);              // 0..47
        const float* wrow = W_xproj + (size_t)jcol * 256 + ((lane >> 4) * 8);
        int mrow = lane & 15;
        f32x4 acc = {0.f, 0.f, 0.f, 0.f};
#pragma unroll
        for (int ks = 0; ks < 8; ks++) {
            bf16x8 af = *(const bf16x8*)(xnb_c + mrow * 512 +
                          ((ks * 64 + ((lane >> 4) * 16)) ^ ((mrow & 7) << 4)));
            f32x4 wa = *(const f32x4*)(wrow + ks * 32);
            f32x4 wb = *(const f32x4*)(wrow + ks * 32 + 4);
            bf16x8 bf;
#pragma unroll
            for (int k = 0; k < 4; k++) { bf[k] = (__bf16)wa[k]; bf[4 + k] = (__bf16)wb[k]; }
            acc = __builtin_amdgcn_mfma_f32_16x16x32_bf16(af, bf, acc, 0, 0, 0);
        }
#pragma unroll
        for (int q = 0; q < 4; q++) {
            int r = (lane >> 4) * 4 + q;
            dbc_s[r * 52 + jcol] = acc[q];
            if (jcol >= 32)      Cc_o[(size_t)(grow0 + r) * 16 + jcol - 32] = acc[q];
            else if (jcol >= 16) Bc_o[(size_t)(grow0 + r) * 16 + jcol - 16] = acc[q];
        }
    }
    __syncthreads();

    // --- Phase C: delta = softplus(dbc[:16] . W_dt[d] + b_dt[d]); pack dxn ---
    int d = tid;
    float wdt[16];
#pragma unroll
    for (int q = 0; q < 4; q++) {
        f32x4 w4 = *(const f32x4*)&W_dt[d * 16 + q * 4];
#pragma unroll
        for (int k = 0; k < 4; k++) wdt[q * 4 + k] = w4[k];
    }
    float bd = b_dt[d];
    float dlt_r[16];
#pragma unroll
    for (int r = 0; r < 16; r++) {
        float din = bd;
#pragma unroll
        for (int k = 0; k < 16; k++) din = fmaf(dbc_s[r * 52 + k], wdt[k], din);
        din = (din > 15.f) ? din : log1pf(__expf(din));
        dlt_r[r] = din;
        union { __bf16 h2[2]; unsigned int u; } pk;
        pk.h2[0] = (__bf16)din;
        pk.h2[1] = (__bf16)xn_s[r * 260 + d];
        dxn[(size_t)(grow0 + r) * D_ + d] = pk.u;
    }

    // --- Phase D: local scan over 16 timesteps (uniform-A fast path) ---
    float ar[16];
#pragma unroll
    for (int q = 0; q < 4; q++) {
        f32x4 a4 = *(const f32x4*)&A_log[d * 16 + q * 4];
#pragma unroll
        for (int k = 0; k < 4; k++) ar[q * 4 + k] = -__expf(a4[k]);
    }
    bool uni = true;
#pragma unroll
    for (int n = 1; n < 16; n++) uni = uni && (ar[n] == ar[0]);
    float s[16], dsum = 0.f;
#pragma unroll
    for (int n = 0; n < 16; n++) s[n] = 0.f;
    if (uni) {
        float ar0 = ar[0];
#pragma unroll
        for (int t = 0; t < CL; t++) {
            float dl = dlt_r[t];
            float dx = dl * xn_s[t * 260 + d];
            dsum += dl;
            float e = __expf(dl * ar0);
#pragma unroll
            for (int n = 0; n < 16; n++)
                s[n] = fmaf(e, s[n], dx * dbc_s[t * 52 + 16 + n]);
        }
    } else {
#pragma unroll
        for (int t = 0; t < CL; t++) {
            float dl = dlt_r[t];
            float dx = dl * xn_s[t * 260 + d];
            dsum += dl;
#pragma unroll
            for (int n = 0; n < 16; n++) {
                float e = __expf(dl * ar[n]);
                s[n] = fmaf(e, s[n], dx * dbc_s[t * 52 + 16 + n]);
            }
        }
    }
    dsum_o[(size_t)blk * 256 + d] = dsum;
    size_t o = (size_t)blk * 4096 + d * 16;
#pragma unroll
    for (int q = 0; q < 4; q++) {
        f32x4 sv;
#pragma unroll
        for (int k = 0; k < 4; k++) sv[k] = s[q*4+k];
        *reinterpret_cast<f32x4*>(&S[o + q * 4]) = sv;
    }
}

// ===== kernel 2: inter-chunk scan (blocks < NBLK) + bf16 table build (blocks >= NBLK)
__global__ __launch_bounds__(256) void k_scan_tab(
        const float* __restrict__ A_log, const float* __restrict__ dsum,
        float* __restrict__ S_H0,
        const float* __restrict__ w_re, const float* __restrict__ w_im,
        __hip_bfloat16* __restrict__ E_t, __hip_bfloat16* __restrict__ wfrag,
        __hip_bfloat16* __restrict__ E_inv)
{
    int blk = blockIdx.x;
    if (blk >= NBLK) {
        int idx = (blk - NBLK) * 256 + threadIdx.x;   // 0..65535
        if (idx < 16384) {
            int x = idx >> 8, d = idx & 255;
            float v = (x < 32) ? __cosf(ANG * (float)((x * d) & 255))
                               : -__sinf(ANG * (float)(((x - 32) * d) & 255));
            E_t[idx] = __float2bfloat16(v);
        } else if (idx < 49152) {
            int f = idx - 16384;
            int nt = f >> 9, l = (f >> 3) & 63, j = f & 7;
            int n = nt * 16 + (l & 15);
            int o = ((l >> 4) & 3) * 8 + j;          // k = o' 0..31
            float v = 0.f;
            if (o < 16) {
                int comp = n >> 9, xm = (n >> 4) & 31, i = n & 15;
                v = comp ? w_im[(i * 16 + o) * 32 + xm] : w_re[(i * 16 + o) * 32 + xm];
            }
            wfrag[f] = __float2bfloat16(v);
        } else {
            int f = idx - 49152;
            int nt = f >> 10, ks = (f >> 9) & 1, l = (f >> 3) & 63, j = f & 7;
            int row = ks * 32 + ((l >> 4) & 3) * 8 + j;
            int col = nt * 16 + (l & 15);
            float v = (row < 32) ? __cosf(ANG * (float)((row * col) & 255))
                                 : -__sinf(ANG * (float)(((row - 32) * col) & 255));
            E_inv[f] = __float2bfloat16(v);
        }
        return;
    }
    __shared__ float gP[256];
    __shared__ float gS[256];
    int tid = threadIdx.x;
    int g2 = tid >> 5, cl2 = tid & 31;
    int ch = blk * 32 + cl2;                      // 512*32 = 16384 channels
    int b2 = ch >> 12, dn2 = ch & 4095;
    int dd = dn2 >> 4;
    float arv = -__expf(A_log[dn2]);
    size_t cb = ((size_t)b2 * NC + g2 * 16) * 4096 + dn2;
    size_t db = ((size_t)b2 * NC + g2 * 16) * 256 + dd;
    float pv[16], sv[16];
#pragma unroll
    for (int c = 0; c < 16; c++) {
        pv[c] = __expf(arv * dsum[db + (size_t)c * 256]);
        sv[c] = S_H0[cb + (size_t)c * 4096];
    }
    float pA = 1.f, sA = 0.f;
#pragma unroll
    for (int c = 0; c < 16; c++) { sA = fmaf(pv[c], sA, sv[c]); pA *= pv[c]; }
    gP[g2 * 32 + cl2] = pA;
    gS[g2 * 32 + cl2] = sA;
    __syncthreads();
    float h = 0.f;
    for (int gg = 0; gg < g2; gg++)
        h = fmaf(gP[gg * 32 + cl2], h, gS[gg * 32 + cl2]);
#pragma unroll
    for (int c = 0; c < 16; c++) {
        S_H0[cb + (size_t)c * 4096] = h;          // H0 for chunk (g2*16+c), in place
        h = fmaf(pv[c], h, sv[c]);
    }
}

// ===== kernel 3: half-chunk re-scan + DFT + wc + g + inverse + epilogue =====
// Grid 1024: block = (chunk = blk&511, half = blk>>9); blocks c and c+512 share
// an XCD (round-robin) so chunk data is L2-shared. Each block owns 8 rows.
// 4 gulps x 2 timesteps; wave (mt=wave&1, nx=wave>>1): m-tile mt, x-cols nx*32..+31.
// LDS map (bytes), 36992 total -> 4 blocks/CU:
//   [0, 16384)      A-tile bf16 [32 m][256 d] swz; wc bf16 [8 r][1024 n] after gulps
//   [16384, 32768)  hf bf16 [8 r][64 x][16 i]
//   [32768, 34944)  gsb bf16 [16][68] (rows 8..15 stale/unused)
//   [34944, 35968)  ccb bf16 [16][32] (rows 8..15 stale/unused)
//   [35968, 36992)  bc_s f32 [16 t][16 n]
__global__ __launch_bounds__(256, 4) void k_fused(
        const unsigned int* __restrict__ dxn,
        const float* __restrict__ xin, const float* __restrict__ D_param,
        const float* __restrict__ Bc, const float* __restrict__ Cc,
        const float* __restrict__ A_log, const float* __restrict__ H0,
        float* __restrict__ out,
        const __hip_bfloat16* __restrict__ E_t, const __hip_bfloat16* __restrict__ wfrag,
        const __hip_bfloat16* __restrict__ E_inv)
{
    __shared__ __align__(16) char smem[36992];
    __bf16* hfb  = (__bf16*)(smem + 16384);
    __bf16* gsb  = (__bf16*)(smem + 32768);
    __bf16* ccb  = (__bf16*)(smem + 34944);
    float*  bc_s = (float*)(smem + 35968);

    int tid = threadIdx.x, wave = tid >> 6, lane = tid & 63;
    int mt = wave & 1, nx = wave >> 1;
    int chunk = blockIdx.x & 511, half = blockIdx.x >> 9;
    int grow0c = chunk * CL;                 // chunk start row
    int row_base = grow0c + half * 8;        // this block's 8 output rows
    int d = tid;

    // ---- setup ----
    bc_s[tid] = Bc[(size_t)grow0c * 16 + tid];
    if (tid < 128) {
        int r = tid >> 4, o = tid & 15;
        float ccv = Cc[(size_t)(row_base + r) * 16 + o];
        ccb[r * 32 + o] = (__bf16)ccv;
        ccb[r * 32 + 16 + o] = (__bf16)0.f;
    }
    unsigned int dxnv[16];
#pragma unroll
    for (int t = 0; t < 16; t++) dxnv[t] = dxn[(size_t)(grow0c + t) * D_ + d];
    float ar[16], h[16];
    {
        size_t ho = (size_t)chunk * 4096 + d * 16;
#pragma unroll
        for (int q = 0; q < 4; q++) {
            f32x4 a4 = *(const f32x4*)&A_log[d * 16 + q * 4];
            f32x4 h4 = *(const f32x4*)&H0[ho + q * 4];
#pragma unroll
            for (int k = 0; k < 4; k++) { ar[q*4+k] = -__expf(a4[k]); h[q*4+k] = h4[k]; }
        }
    }
    bool uni = true;
#pragma unroll
    for (int n = 1; n < 16; n++) uni = uni && (ar[n] == ar[0]);
    float ar0 = ar[0];

    // ---- E fragments for this wave's 32 x-columns (VGPR-resident) ----
    bf16x8 bfragAll[2][8];
#pragma unroll
    for (int nt2 = 0; nt2 < 2; nt2++) {
        int xa = nx * 32 + nt2 * 16 + (lane & 15);
#pragma unroll
        for (int ks = 0; ks < 8; ks++)
            bfragAll[nt2][ks] = *(const bf16x8*)(E_t + xa * 256 + ks * 32 + ((lane >> 4) * 8));
    }
    int swz = (lane & 7) << 4;
    f32x4 acc[2];
#pragma unroll
    for (int b = 0; b < 2; b++) { acc[b][0]=0.f; acc[b][1]=0.f; acc[b][2]=0.f; acc[b][3]=0.f; }

    // ---- silent scan of the other half's prefix (upper-half blocks only) ----
    if (half) {
        if (uni) {
#pragma unroll
            for (int t = 0; t < 8; t++) {
                unsigned int v = dxnv[t];
                float dl = __uint_as_float(v << 16);
                float dx = dl * __uint_as_float(v & 0xffff0000u);
                float e = __expf(dl * ar0);
#pragma unroll
                for (int n = 0; n < 16; n++)
                    h[n] = fmaf(e, h[n], dx * bc_s[t * 16 + n]);
            }
        } else {
#pragma unroll
            for (int t = 0; t < 8; t++) {
                unsigned int v = dxnv[t];
                float dl = __uint_as_float(v << 16);
                float dx = dl * __uint_as_float(v & 0xffff0000u);
#pragma unroll
                for (int n = 0; n < 16; n++) {
                    float e = __expf(dl * ar[n]);
                    h[n] = fmaf(e, h[n], dx * bc_s[t * 16 + n]);
                }
            }
        }
    }
    __syncthreads();   // bc_s/ccb ready (and A-region safe to write)

    // ---- 4 gulps x 2 timesteps: scan -> A-tile; DFT MFMA -> hf [r][x][i] ----
#pragma unroll
    for (int g = 0; g < 4; g++) {
#pragma unroll
        for (int tl = 0; tl < 2; tl++) {
            int t = half * 8 + g * 2 + tl;
            unsigned int v = dxnv[t];
            float dl = __uint_as_float(v << 16);
            float dx = dl * __uint_as_float(v & 0xffff0000u);
            if (uni) {
                float e = __expf(dl * ar0);
#pragma unroll
                for (int n = 0; n < 16; n++) {
                    h[n] = fmaf(e, h[n], dx * bc_s[t * 16 + n]);
                    int m = tl * 16 + n;
                    *(__bf16*)(smem + m * 512 + ((d * 2) ^ ((m & 7) << 4))) = (__bf16)h[n];
                }
            } else {
#pragma unroll
                for (int n = 0; n < 16; n++) {
                    float e = __expf(dl * ar[n]);
                    h[n] = fmaf(e, h[n], dx * bc_s[t * 16 + n]);
                    int m = tl * 16 + n;
                    *(__bf16*)(smem + m * 512 + ((d * 2) ^ ((m & 7) << 4))) = (__bf16)h[n];
                }
            }
        }
        __syncthreads();
        // DFT MFMA: wave's m-tile = mt (timestep), x-cols nx*32..+31
#pragma unroll
        for (int ks = 0; ks < 8; ks++) {
            int m = mt * 16 + (lane & 15);
            bf16x8 af = *(const bf16x8*)(smem + m * 512 + ((ks * 64 + ((lane >> 4) * 16)) ^ swz));
#pragma unroll
            for (int nt2 = 0; nt2 < 2; nt2++)
                acc[nt2] = __builtin_amdgcn_mfma_f32_16x16x32_bf16(af, bfragAll[nt2][ks], acc[nt2], 0, 0, 0);
        }
        {
            int r = g * 2 + mt;   // local row 0..7
#pragma unroll
            for (int nt2 = 0; nt2 < 2; nt2++) {
                int xcol = nx * 32 + nt2 * 16 + (lane & 15);
                bf16x4 pk;
#pragma unroll
                for (int k = 0; k < 4; k++) { pk[k] = (__bf16)acc[nt2][k]; acc[nt2][k] = 0.f; }
                *(bf16x4*)(&hfb[r * 1024 + xcol * 16 + (lane >> 4) * 4]) = pk;
            }
        }
        __syncthreads();
    }

    // ---- prefetch epilogue inputs (hide HBM latency under wc+g) ----
    float xpf[4][4], xnpf[4][4], dpf[4];
#pragma unroll
    for (int ntl = 0; ntl < 4; ntl++) {
        int dcol = (wave * 4 + ntl) * 16 + (lane & 15);
        dpf[ntl] = D_param[dcol];
#pragma unroll
        for (int q = 0; q < 4; q++) {
            int r = (lane >> 4) * 4 + q;
            if (r < 8) {
                size_t go = (size_t)(row_base + r) * D_ + dcol;
                xpf[ntl][q] = xin[go];
                xnpf[ntl][q] = __uint_as_float(dxn[go] & 0xffff0000u);
            } else { xpf[ntl][q] = 0.f; xnpf[ntl][q] = 0.f; }
        }
    }

    // ---- wc = Cc @ w via MFMA (8 valid rows), into dead A-tile region ----
    {
        bf16x8 ccf = *(const bf16x8*)((char*)ccb + (lane & 15) * 64 + ((lane >> 4) * 16));
#pragma unroll
        for (int ntl = 0; ntl < 16; ntl++) {
            int nt = wave * 16 + ntl;
            f32x4 a = {0.f, 0.f, 0.f, 0.f};
            bf16x8 wf = *(const bf16x8*)(wfrag + (nt * 64 + lane) * 8);
            a = __builtin_amdgcn_mfma_f32_16x16x32_bf16(ccf, wf, a, 0, 0, 0);
            int col = nt * 16 + (lane & 15);
#pragma unroll
            for (int q = 0; q < 4; q++) {
                int r = (lane >> 4) * 4 + q;
                if (r < 8) *(__bf16*)(smem + r * 2048 + col * 2) = (__bf16)a[q];
            }
        }
    }
    __syncthreads();

    // ---- g[r,x] = sum_i hf[r,x,i] * wc[r,x,i] (complex); thread = (r, 1 x) ----
    {
        __bf16* wcb = (__bf16*)smem;
        int r = tid >> 5, xs = tid & 31;
        bf16x8 hra = *(const bf16x8*)(&hfb[r * 1024 + xs * 16]);
        bf16x8 hrb = *(const bf16x8*)(&hfb[r * 1024 + xs * 16 + 8]);
        bf16x8 hia = *(const bf16x8*)(&hfb[r * 1024 + (xs + 32) * 16]);
        bf16x8 hib = *(const bf16x8*)(&hfb[r * 1024 + (xs + 32) * 16 + 8]);
        bf16x8 wra = *(const bf16x8*)(&wcb[r * 1024 + xs * 16]);
        bf16x8 wrb = *(const bf16x8*)(&wcb[r * 1024 + xs * 16 + 8]);
        bf16x8 wia = *(const bf16x8*)(&wcb[r * 1024 + 512 + xs * 16]);
        bf16x8 wib = *(const bf16x8*)(&wcb[r * 1024 + 512 + xs * 16 + 8]);
        float gre = 0.f, gim = 0.f;
#pragma unroll
        for (int k = 0; k < 8; k++) {
            float hr = (float)hra[k], hi = (float)hia[k];
            float wr = (float)wra[k], wi = (float)wia[k];
            gre = fmaf(hr, wr, gre); gre = fmaf(-hi, wi, gre);
            gim = fmaf(hr, wi, gim); gim = fmaf(hi, wr, gim);
            float hr2 = (float)hrb[k], hi2 = (float)hib[k];
            float wr2 = (float)wrb[k], wi2 = (float)wib[k];
            gre = fmaf(hr2, wr2, gre); gre = fmaf(-hi2, wi2, gre);
            gim = fmaf(hr2, wi2, gim); gim = fmaf(hi2, wr2, gim);
        }
        float sc = xs ? 2.f : 1.f;
        gsb[r * 68 + xs]      = (__bf16)(gre * sc);
        gsb[r * 68 + 32 + xs] = (__bf16)(gim * sc);
    }
    __syncthreads();

    // ---- inverse DFT via MFMA (8 valid rows) + epilogue ----
    {
        bf16x8 ga0 = *(const bf16x8*)((char*)gsb + (lane & 15) * 136 + ((lane >> 4) * 16));
        bf16x8 ga1 = *(const bf16x8*)((char*)gsb + (lane & 15) * 136 + 64 + ((lane >> 4) * 16));
#pragma unroll
        for (int ntl = 0; ntl < 4; ntl++) {
            int nt = wave * 4 + ntl;
            f32x4 a = {0.f, 0.f, 0.f, 0.f};
            a = __builtin_amdgcn_mfma_f32_16x16x32_bf16(
                    ga0, *(const bf16x8*)(E_inv + ((nt * 2 + 0) * 64 + lane) * 8), a, 0, 0, 0);
            a = __builtin_amdgcn_mfma_f32_16x16x32_bf16(
                    ga1, *(const bf16x8*)(E_inv + ((nt * 2 + 1) * 64 + lane) * 8), a, 0, 0, 0);
            int dcol = nt * 16 + (lane & 15);
#pragma unroll
            for (int q = 0; q < 4; q++) {
                int r = (lane >> 4) * 4 + q;
                if (r < 8) {
                    size_t go = (size_t)(row_base + r) * D_ + dcol;
                    out[go] = xpf[ntl][q] + dpf[ntl] * xnpf[ntl][q] + a[q] * (1.f / 256.f);
                }
            }
        }
    }
}

// ===== launch =====
extern "C" void kernel_launch(void* const* d_in, const int* in_sizes, int n_in,
                              void* d_out, int out_size, void* d_ws, size_t ws_size,
                              hipStream_t stream)
{
    const float* x       = (const float*)d_in[0];
    const float* ln_g    = (const float*)d_in[1];
    const float* ln_b    = (const float*)d_in[2];
    const float* W_xproj = (const float*)d_in[3];
    const float* W_dt    = (const float*)d_in[4];
    const float* b_dt    = (const float*)d_in[5];
    const float* A_log   = (const float*)d_in[6];
    const float* D_param = (const float*)d_in[7];
    const float* w_re    = (const float*)d_in[8];
    const float* w_im    = (const float*)d_in[9];

    float* ws    = (float*)d_ws;
    float* S_H0  = ws;                               // 2M floats (S, then H0 in place)
    unsigned int* dxn = (unsigned int*)(S_H0 + 2097152); // 2M u32 (bf16 dlt | bf16 xn)
    float* Bc    = (float*)(dxn + 2097152);          // 131072
    float* Cc    = Bc + 131072;                      // 131072
    float* dsum  = Cc + 131072;                      // 131072
    __hip_bfloat16* tab = (__hip_bfloat16*)(dsum + 131072);
    __hip_bfloat16* E_t   = tab;                     // 16384 bf16
    __hip_bfloat16* wfrag = tab + 16384;             // 32768
    __hip_bfloat16* E_inv = tab + 49152;             // 16384
    float* out = (float*)d_out;

    hipLaunchKernelGGL(k_lnscan, dim3(NBLK), dim3(256), 0, stream,
                       x, ln_g, ln_b, W_xproj, W_dt, b_dt, A_log,
                       dxn, Bc, Cc, dsum, S_H0);
    hipLaunchKernelGGL(k_scan_tab, dim3(NBLK + 256), dim3(256), 0, stream,
                       A_log, dsum, S_H0, w_re, w_im, E_t, wfrag, E_inv);
    hipLaunchKernelGGL(k_fused, dim3(2 * NBLK), dim3(256), 0, stream,
                       dxn, x, D_param, Bc, Cc, A_log, S_H0, out, E_t, wfrag, E_inv);
}

// Round 13
// 52.785 us; speedup vs baseline: 1.6350x; 1.6350x over previous
//
#include <hip/hip_runtime.h>
#include <hip/hip_bf16.h>

// Problem constants
#define B_   4
#define L_   2048
#define D_   256
#define NC   128
#define CL   16
#define NBLK (B_*NC)   // 512 chunks
#define ANG  0.02454369260617025967f   // 2*pi/256

typedef __bf16 bf16x8 __attribute__((ext_vector_type(8)));
typedef __bf16 bf16x4 __attribute__((ext_vector_type(4)));
typedef float  f32x4  __attribute__((ext_vector_type(4)));

// ===== kernel 1: LN + proj(MFMA, inline W-frags) + delta + local scan =====
__global__ __launch_bounds__(256) void k_lnscan(
        const float* __restrict__ x, const float* __restrict__ ln_g, const float* __restrict__ ln_b,
        const float* __restrict__ W_xproj, const float* __restrict__ W_dt,
        const float* __restrict__ b_dt, const float* __restrict__ A_log,
        unsigned int* __restrict__ dxn,
        float* __restrict__ Bc_o, float* __restrict__ Cc_o,
        float* __restrict__ dsum_o, float* __restrict__ S)
{
    __shared__ __align__(16) float xn_s[16 * 260];   // stride 260 -> conflict-free
    __shared__ __align__(16) __bf16 xnb[16 * 256];   // bf16 A-tile [m][d], XOR-swizzled
    __shared__ float dbc_s[16 * 52];
    int tid = threadIdx.x, wave = tid >> 6, lane = tid & 63;
    int blk = blockIdx.x;
    int grow0 = blk * CL;
    char* xnb_c = (char*)xnb;

    // --- Phase A: LayerNorm, 4 rows per wave ---
#pragma unroll
    for (int rr = 0; rr < 4; rr++) {
        int r = wave * 4 + rr;
        const float* xr = x + (size_t)(grow0 + r) * D_;
        float v[4];
#pragma unroll
        for (int q = 0; q < 4; q++) v[q] = xr[lane + q * 64];
        float sum = v[0] + v[1] + v[2] + v[3];
        float sq  = v[0]*v[0] + v[1]*v[1] + v[2]*v[2] + v[3]*v[3];
#pragma unroll
        for (int off = 32; off; off >>= 1) { sum += __shfl_xor(sum, off); sq += __shfl_xor(sq, off); }
        float mu = sum * (1.f / D_);
        float rstd = rsqrtf(sq * (1.f / D_) - mu * mu + 1e-5f);
#pragma unroll
        for (int q = 0; q < 4; q++) {
            int d = lane + q * 64;
            float xv = (v[q] - mu) * rstd * ln_g[d] + ln_b[d];
            xn_s[r * 260 + d] = xv;
            *(__bf16*)(xnb_c + r * 512 + ((d * 2) ^ ((r & 7) << 4))) = (__bf16)xv;
        }
    }
    __syncthreads();

    // --- Phase B: dbc = xn @ W_xproj^T via MFMA; W-frags inlined ---
    if (wave < 3) {
        int jcol = wave * 16 + (lane & 15);              // 0..47
        const float* wrow = W_xproj + (size_t)jcol * 256 + ((lane >> 4) * 8);
        int mrow = lane & 15;
        f32x4 acc = {0.f, 0.f, 0.f, 0.f};
#pragma unroll
        for (int ks = 0; ks < 8; ks++) {
            bf16x8 af = *(const bf16x8*)(xnb_c + mrow * 512 +
                          ((ks * 64 + ((lane >> 4) * 16)) ^ ((mrow & 7) << 4)));
            f32x4 wa = *(const f32x4*)(wrow + ks * 32);
            f32x4 wb = *(const f32x4*)(wrow + ks * 32 + 4);
            bf16x8 bf;
#pragma unroll
            for (int k = 0; k < 4; k++) { bf[k] = (__bf16)wa[k]; bf[4 + k] = (__bf16)wb[k]; }
            acc = __builtin_amdgcn_mfma_f32_16x16x32_bf16(af, bf, acc, 0, 0, 0);
        }
#pragma unroll
        for (int q = 0; q < 4; q++) {
            int r = (lane >> 4) * 4 + q;
            dbc_s[r * 52 + jcol] = acc[q];
            if (jcol >= 32)      Cc_o[(size_t)(grow0 + r) * 16 + jcol - 32] = acc[q];
            else if (jcol >= 16) Bc_o[(size_t)(grow0 + r) * 16 + jcol - 16] = acc[q];
        }
    }
    __syncthreads();

    // --- Phase C: delta = softplus(dbc[:16] . W_dt[d] + b_dt[d]); pack dxn ---
    int d = tid;
    float wdt[16];
#pragma unroll
    for (int q = 0; q < 4; q++) {
        f32x4 w4 = *(const f32x4*)&W_dt[d * 16 + q * 4];
#pragma unroll
        for (int k = 0; k < 4; k++) wdt[q * 4 + k] = w4[k];
    }
    float bd = b_dt[d];
    float dlt_r[16];
#pragma unroll
    for (int r = 0; r < 16; r++) {
        float din = bd;
#pragma unroll
        for (int k = 0; k < 16; k++) din = fmaf(dbc_s[r * 52 + k], wdt[k], din);
        din = (din > 15.f) ? din : log1pf(__expf(din));
        dlt_r[r] = din;
        union { __bf16 h2[2]; unsigned int u; } pk;
        pk.h2[0] = (__bf16)din;
        pk.h2[1] = (__bf16)xn_s[r * 260 + d];
        dxn[(size_t)(grow0 + r) * D_ + d] = pk.u;
    }

    // --- Phase D: local scan over 16 timesteps (uniform-A fast path) ---
    float ar[16];
#pragma unroll
    for (int q = 0; q < 4; q++) {
        f32x4 a4 = *(const f32x4*)&A_log[d * 16 + q * 4];
#pragma unroll
        for (int k = 0; k < 4; k++) ar[q * 4 + k] = -__expf(a4[k]);
    }
    bool uni = true;
#pragma unroll
    for (int n = 1; n < 16; n++) uni = uni && (ar[n] == ar[0]);
    float s[16], dsum = 0.f;
#pragma unroll
    for (int n = 0; n < 16; n++) s[n] = 0.f;
    if (uni) {
        float ar0 = ar[0];
#pragma unroll
        for (int t = 0; t < CL; t++) {
            float dl = dlt_r[t];
            float dx = dl * xn_s[t * 260 + d];
            dsum += dl;
            float e = __expf(dl * ar0);
#pragma unroll
            for (int n = 0; n < 16; n++)
                s[n] = fmaf(e, s[n], dx * dbc_s[t * 52 + 16 + n]);
        }
    } else {
#pragma unroll
        for (int t = 0; t < CL; t++) {
            float dl = dlt_r[t];
            float dx = dl * xn_s[t * 260 + d];
            dsum += dl;
#pragma unroll
            for (int n = 0; n < 16; n++) {
                float e = __expf(dl * ar[n]);
                s[n] = fmaf(e, s[n], dx * dbc_s[t * 52 + 16 + n]);
            }
        }
    }
    dsum_o[(size_t)blk * 256 + d] = dsum;
    size_t o = (size_t)blk * 4096 + d * 16;
#pragma unroll
    for (int q = 0; q < 4; q++) {
        f32x4 sv;
#pragma unroll
        for (int k = 0; k < 4; k++) sv[k] = s[q*4+k];
        *reinterpret_cast<f32x4*>(&S[o + q * 4]) = sv;
    }
}

// ===== kernel 2: inter-chunk scan (blocks < NBLK) + bf16 table build (blocks >= NBLK)
__global__ __launch_bounds__(256) void k_scan_tab(
        const float* __restrict__ A_log, const float* __restrict__ dsum,
        float* __restrict__ S_H0,
        const float* __restrict__ w_re, const float* __restrict__ w_im,
        __hip_bfloat16* __restrict__ E_t, __hip_bfloat16* __restrict__ wfrag,
        __hip_bfloat16* __restrict__ E_inv)
{
    int blk = blockIdx.x;
    if (blk >= NBLK) {
        int idx = (blk - NBLK) * 256 + threadIdx.x;   // 0..65535
        if (idx < 16384) {
            int x = idx >> 8, d = idx & 255;
            float v = (x < 32) ? __cosf(ANG * (float)((x * d) & 255))
                               : -__sinf(ANG * (float)(((x - 32) * d) & 255));
            E_t[idx] = __float2bfloat16(v);
        } else if (idx < 49152) {
            int f = idx - 16384;
            int nt = f >> 9, l = (f >> 3) & 63, j = f & 7;
            int n = nt * 16 + (l & 15);
            int o = ((l >> 4) & 3) * 8 + j;          // k = o' 0..31
            float v = 0.f;
            if (o < 16) {
                int comp = n >> 9, xm = (n >> 4) & 31, i = n & 15;
                v = comp ? w_im[(i * 16 + o) * 32 + xm] : w_re[(i * 16 + o) * 32 + xm];
            }
            wfrag[f] = __float2bfloat16(v);
        } else {
            int f = idx - 49152;
            int nt = f >> 10, ks = (f >> 9) & 1, l = (f >> 3) & 63, j = f & 7;
            int row = ks * 32 + ((l >> 4) & 3) * 8 + j;
            int col = nt * 16 + (l & 15);
            float v = (row < 32) ? __cosf(ANG * (float)((row * col) & 255))
                                 : -__sinf(ANG * (float)(((row - 32) * col) & 255));
            E_inv[f] = __float2bfloat16(v);
        }
        return;
    }
    __shared__ float gP[256];
    __shared__ float gS[256];
    int tid = threadIdx.x;
    int g2 = tid >> 5, cl2 = tid & 31;
    int ch = blk * 32 + cl2;                      // 512*32 = 16384 channels
    int b2 = ch >> 12, dn2 = ch & 4095;
    int dd = dn2 >> 4;
    float arv = -__expf(A_log[dn2]);
    size_t cb = ((size_t)b2 * NC + g2 * 16) * 4096 + dn2;
    size_t db = ((size_t)b2 * NC + g2 * 16) * 256 + dd;
    float pv[16], sv[16];
#pragma unroll
    for (int c = 0; c < 16; c++) {
        pv[c] = __expf(arv * dsum[db + (size_t)c * 256]);
        sv[c] = S_H0[cb + (size_t)c * 4096];
    }
    float pA = 1.f, sA = 0.f;
#pragma unroll
    for (int c = 0; c < 16; c++) { sA = fmaf(pv[c], sA, sv[c]); pA *= pv[c]; }
    gP[g2 * 32 + cl2] = pA;
    gS[g2 * 32 + cl2] = sA;
    __syncthreads();
    float h = 0.f;
    for (int gg = 0; gg < g2; gg++)
        h = fmaf(gP[gg * 32 + cl2], h, gS[gg * 32 + cl2]);
#pragma unroll
    for (int c = 0; c < 16; c++) {
        S_H0[cb + (size_t)c * 4096] = h;          // H0 for chunk (g2*16+c), in place
        h = fmaf(pv[c], h, sv[c]);
    }
}

// ===== kernel 3: re-scan + DFT(MFMA) + wc(MFMA, 2 comp-phases) + g + inverse + epilogue
// 512 blocks (full chunk each); 8 gulps x 2 timesteps; LDS 53376 B -> 3 blocks/CU.
// Wave (mt=wave&1, nx=wave>>1): m-tile mt, x-cols nx*32..+31.
// LDS map (bytes):
//   [0, 16384)      A-tile bf16 [32 m][256 d] swz; then wc bf16 [16 r][512 n'] per comp-phase
//   [16384, 49152)  hf bf16 [16 r][64 x][16 i]
//   [49152, 51328)  gsb bf16 [16 r][68]
//   [51328, 52352)  ccb bf16 [16 r][32 o']
//   [52352, 53376)  bc_s f32 [16 t][16 n]
__global__ __launch_bounds__(256, 3) void k_fused(
        const unsigned int* __restrict__ dxn,
        const float* __restrict__ xin, const float* __restrict__ D_param,
        const float* __restrict__ Bc, const float* __restrict__ Cc,
        const float* __restrict__ A_log, const float* __restrict__ H0,
        float* __restrict__ out,
        const __hip_bfloat16* __restrict__ E_t, const __hip_bfloat16* __restrict__ wfrag,
        const __hip_bfloat16* __restrict__ E_inv)
{
    __shared__ __align__(16) char smem[53376];
    __bf16* hfb  = (__bf16*)(smem + 16384);
    __bf16* gsb  = (__bf16*)(smem + 49152);
    __bf16* ccb  = (__bf16*)(smem + 51328);
    float*  bc_s = (float*)(smem + 52352);

    int tid = threadIdx.x, wave = tid >> 6, lane = tid & 63;
    int mt = wave & 1, nx = wave >> 1;
    int blk = blockIdx.x;
    int grow0 = blk * CL;
    int d = tid;

    // ---- setup ----
    bc_s[tid] = Bc[(size_t)grow0 * 16 + tid];
    {
        float ccv = Cc[(size_t)grow0 * 16 + tid];
        int r = tid >> 4, o = tid & 15;
        ccb[r * 32 + o] = (__bf16)ccv;
        ccb[r * 32 + 16 + o] = (__bf16)0.f;
    }
    unsigned int dxnv[16];
#pragma unroll
    for (int t = 0; t < 16; t++) dxnv[t] = dxn[(size_t)(grow0 + t) * D_ + d];
    float ar[16], h[16];
    {
        size_t ho = (size_t)blk * 4096 + d * 16;
#pragma unroll
        for (int q = 0; q < 4; q++) {
            f32x4 a4 = *(const f32x4*)&A_log[d * 16 + q * 4];
            f32x4 h4 = *(const f32x4*)&H0[ho + q * 4];
#pragma unroll
            for (int k = 0; k < 4; k++) { ar[q*4+k] = -__expf(a4[k]); h[q*4+k] = h4[k]; }
        }
    }
    bool uni = true;
#pragma unroll
    for (int n = 1; n < 16; n++) uni = uni && (ar[n] == ar[0]);
    float ar0 = ar[0];

    // ---- E fragments for this wave's 32 x-columns (VGPR-resident) ----
    bf16x8 bfragAll[2][8];
#pragma unroll
    for (int nt2 = 0; nt2 < 2; nt2++) {
        int xa = nx * 32 + nt2 * 16 + (lane & 15);
#pragma unroll
        for (int ks = 0; ks < 8; ks++)
            bfragAll[nt2][ks] = *(const bf16x8*)(E_t + xa * 256 + ks * 32 + ((lane >> 4) * 8));
    }
    int swz = (lane & 7) << 4;
    f32x4 acc[2];
#pragma unroll
    for (int b = 0; b < 2; b++) { acc[b][0]=0.f; acc[b][1]=0.f; acc[b][2]=0.f; acc[b][3]=0.f; }
    __syncthreads();

    // ---- 8 gulps x 2 timesteps: scan -> A-tile; DFT MFMA -> hf [r][x][i] ----
#pragma unroll
    for (int g = 0; g < 8; g++) {
#pragma unroll
        for (int tl = 0; tl < 2; tl++) {
            int t = g * 2 + tl;
            unsigned int v = dxnv[t];
            float dl = __uint_as_float(v << 16);
            float dx = dl * __uint_as_float(v & 0xffff0000u);
            if (uni) {
                float e = __expf(dl * ar0);
#pragma unroll
                for (int n = 0; n < 16; n++) {
                    h[n] = fmaf(e, h[n], dx * bc_s[t * 16 + n]);
                    int m = tl * 16 + n;
                    *(__bf16*)(smem + m * 512 + ((d * 2) ^ ((m & 7) << 4))) = (__bf16)h[n];
                }
            } else {
#pragma unroll
                for (int n = 0; n < 16; n++) {
                    float e = __expf(dl * ar[n]);
                    h[n] = fmaf(e, h[n], dx * bc_s[t * 16 + n]);
                    int m = tl * 16 + n;
                    *(__bf16*)(smem + m * 512 + ((d * 2) ^ ((m & 7) << 4))) = (__bf16)h[n];
                }
            }
        }
        __syncthreads();
        // DFT MFMA: wave's m-tile = mt (timestep within gulp), x-cols nx*32..+31
#pragma unroll
        for (int ks = 0; ks < 8; ks++) {
            int m = mt * 16 + (lane & 15);
            bf16x8 af = *(const bf16x8*)(smem + m * 512 + ((ks * 64 + ((lane >> 4) * 16)) ^ swz));
#pragma unroll
            for (int nt2 = 0; nt2 < 2; nt2++)
                acc[nt2] = __builtin_amdgcn_mfma_f32_16x16x32_bf16(af, bfragAll[nt2][ks], acc[nt2], 0, 0, 0);
        }
        {
            int r = g * 2 + mt;
#pragma unroll
            for (int nt2 = 0; nt2 < 2; nt2++) {
                int xcol = nx * 32 + nt2 * 16 + (lane & 15);
                bf16x4 pk;
#pragma unroll
                for (int k = 0; k < 4; k++) { pk[k] = (__bf16)acc[nt2][k]; acc[nt2][k] = 0.f; }
                *(bf16x4*)(&hfb[r * 1024 + xcol * 16 + (lane >> 4) * 4]) = pk;
            }
        }
        __syncthreads();
    }

    // ---- prefetch epilogue inputs (hide HBM latency under wc+g) ----
    float xpf[4][4], xnpf[4][4], dpf[4];
#pragma unroll
    for (int ntl = 0; ntl < 4; ntl++) {
        int dcol = (wave * 4 + ntl) * 16 + (lane & 15);
        dpf[ntl] = D_param[dcol];
#pragma unroll
        for (int q = 0; q < 4; q++) {
            int r = (lane >> 4) * 4 + q;
            size_t go = (size_t)(grow0 + r) * D_ + dcol;
            xpf[ntl][q] = xin[go];
            xnpf[ntl][q] = __uint_as_float(dxn[go] & 0xffff0000u);
        }
    }

    // ---- wc + g in two comp-phases (re, then im); g accumulators in registers ----
    float gre[2], gim[2];
    gre[0] = gre[1] = gim[0] = gim[1] = 0.f;
    bf16x8 ccf = *(const bf16x8*)((char*)ccb + (lane & 15) * 64 + ((lane >> 4) * 16));
    int gr = tid >> 4, gx2 = tid & 15;
#pragma unroll
    for (int comp = 0; comp < 2; comp++) {
        // wc_comp = Cc @ w (nt = comp*32 + wave*8 + ntl) -> A-region [16 r][512 n']
#pragma unroll
        for (int ntl = 0; ntl < 8; ntl++) {
            int nt = comp * 32 + wave * 8 + ntl;
            f32x4 a = {0.f, 0.f, 0.f, 0.f};
            bf16x8 wf = *(const bf16x8*)(wfrag + (nt * 64 + lane) * 8);
            a = __builtin_amdgcn_mfma_f32_16x16x32_bf16(ccf, wf, a, 0, 0, 0);
            int coln = (nt - comp * 32) * 16 + (lane & 15);   // 0..511
#pragma unroll
            for (int q = 0; q < 4; q++) {
                int r = (lane >> 4) * 4 + q;
                *(__bf16*)(smem + r * 1024 + coln * 2) = (__bf16)a[q];
            }
        }
        __syncthreads();
        // g partial: thread = (gr, 2 x's)
        __bf16* wcb = (__bf16*)smem;
#pragma unroll
        for (int xh = 0; xh < 2; xh++) {
            int xs = xh * 16 + gx2;
            bf16x8 hra = *(const bf16x8*)(&hfb[gr * 1024 + xs * 16]);
            bf16x8 hrb = *(const bf16x8*)(&hfb[gr * 1024 + xs * 16 + 8]);
            bf16x8 hia = *(const bf16x8*)(&hfb[gr * 1024 + (xs + 32) * 16]);
            bf16x8 hib = *(const bf16x8*)(&hfb[gr * 1024 + (xs + 32) * 16 + 8]);
            bf16x8 wva = *(const bf16x8*)(&wcb[gr * 512 + xs * 16]);
            bf16x8 wvb = *(const bf16x8*)(&wcb[gr * 512 + xs * 16 + 8]);
            float sre = 0.f, sim = 0.f;
#pragma unroll
            for (int k = 0; k < 8; k++) {
                float hr = (float)hra[k], hi = (float)hia[k], wv = (float)wva[k];
                sre = fmaf(hr, wv, sre); sim = fmaf(hi, wv, sim);
                float hr2 = (float)hrb[k], hi2 = (float)hib[k], wv2 = (float)wvb[k];
                sre = fmaf(hr2, wv2, sre); sim = fmaf(hi2, wv2, sim);
            }
            if (comp == 0) { gre[xh] += sre; gim[xh] += sim; }   // w_re: gre += hr*wr, gim += hi*wr
            else           { gre[xh] -= sim; gim[xh] += sre; }   // w_im: gre -= hi*wi, gim += hr*wi
        }
        __syncthreads();
    }
    // write gsb
#pragma unroll
    for (int xh = 0; xh < 2; xh++) {
        int xs = xh * 16 + gx2;
        float sc = xs ? 2.f : 1.f;
        gsb[gr * 68 + xs]      = (__bf16)(gre[xh] * sc);
        gsb[gr * 68 + 32 + xs] = (__bf16)(gim[xh] * sc);
    }
    __syncthreads();

    // ---- inverse DFT via MFMA (M=16 r, K=64, N=256 d') + epilogue ----
    {
        bf16x8 ga0 = *(const bf16x8*)((char*)gsb + (lane & 15) * 136 + ((lane >> 4) * 16));
        bf16x8 ga1 = *(const bf16x8*)((char*)gsb + (lane & 15) * 136 + 64 + ((lane >> 4) * 16));
#pragma unroll
        for (int ntl = 0; ntl < 4; ntl++) {
            int nt = wave * 4 + ntl;
            f32x4 a = {0.f, 0.f, 0.f, 0.f};
            a = __builtin_amdgcn_mfma_f32_16x16x32_bf16(
                    ga0, *(const bf16x8*)(E_inv + ((nt * 2 + 0) * 64 + lane) * 8), a, 0, 0, 0);
            a = __builtin_amdgcn_mfma_f32_16x16x32_bf16(
                    ga1, *(const bf16x8*)(E_inv + ((nt * 2 + 1) * 64 + lane) * 8), a, 0, 0, 0);
            int dcol = nt * 16 + (lane & 15);
#pragma unroll
            for (int q = 0; q < 4; q++) {
                int r = (lane >> 4) * 4 + q;
                size_t go = (size_t)(grow0 + r) * D_ + dcol;
                out[go] = xpf[ntl][q] + dpf[ntl] * xnpf[ntl][q] + a[q] * (1.f / 256.f);
            }
        }
    }
}

// ===== launch =====
extern "C" void kernel_launch(void* const* d_in, const int* in_sizes, int n_in,
                              void* d_out, int out_size, void* d_ws, size_t ws_size,
                              hipStream_t stream)
{
    const float* x       = (const float*)d_in[0];
    const float* ln_g    = (const float*)d_in[1];
    const float* ln_b    = (const float*)d_in[2];
    const float* W_xproj = (const float*)d_in[3];
    const float* W_dt    = (const float*)d_in[4];
    const float* b_dt    = (const float*)d_in[5];
    const float* A_log   = (const float*)d_in[6];
    const float* D_param = (const float*)d_in[7];
    const float* w_re    = (const float*)d_in[8];
    const float* w_im    = (const float*)d_in[9];

    float* ws    = (float*)d_ws;
    float* S_H0  = ws;                               // 2M floats (S, then H0 in place)
    unsigned int* dxn = (unsigned int*)(S_H0 + 2097152); // 2M u32 (bf16 dlt | bf16 xn)
    float* Bc    = (float*)(dxn + 2097152);          // 131072
    float* Cc    = Bc + 131072;                      // 131072
    float* dsum  = Cc + 131072;                      // 131072
    __hip_bfloat16* tab = (__hip_bfloat16*)(dsum + 131072);
    __hip_bfloat16* E_t   = tab;                     // 16384 bf16
    __hip_bfloat16* wfrag = tab + 16384;             // 32768
    __hip_bfloat16* E_inv = tab + 49152;             // 16384
    float* out = (float*)d_out;

    hipLaunchKernelGGL(k_lnscan, dim3(NBLK), dim3(256), 0, stream,
                       x, ln_g, ln_b, W_xproj, W_dt, b_dt, A_log,
                       dxn, Bc, Cc, dsum, S_H0);
    hipLaunchKernelGGL(k_scan_tab, dim3(NBLK + 256), dim3(256), 0, stream,
                       A_log, dsum, S_H0, w_re, w_im, E_t, wfrag, E_inv);
    hipLaunchKernelGGL(k_fused, dim3(NBLK), dim3(256), 0, stream,
                       dxn, x, D_param, Bc, Cc, A_log, S_H0, out, E_t, wfrag, E_inv);
}

// Round 14
// 45.731 us; speedup vs baseline: 1.8872x; 1.1542x over previous
//
#include <hip/hip_runtime.h>
#include <hip/hip_bf16.h>

// Problem constants
#define B_   4
#define L_   2048
#define D_   256
#define NC   128
#define CL   16
#define NBLK (B_*NC)   // 512 chunks
#define ANG  0.02454369260617025967f   // 2*pi/256

typedef __bf16 bf16x8 __attribute__((ext_vector_type(8)));
typedef __bf16 bf16x4 __attribute__((ext_vector_type(4)));
typedef float  f32x4  __attribute__((ext_vector_type(4)));

// ===== kernel 1: LN + proj(MFMA, inline W-frags) + delta + local scan;
//       blocks >= NBLK build the bf16 fragment tables (consumed by k_fused) =====
__global__ __launch_bounds__(256) void k_lnscan(
        const float* __restrict__ x, const float* __restrict__ ln_g, const float* __restrict__ ln_b,
        const float* __restrict__ W_xproj, const float* __restrict__ W_dt,
        const float* __restrict__ b_dt, const float* __restrict__ A_log,
        unsigned int* __restrict__ dxn,
        float* __restrict__ Bc_o, float* __restrict__ Cc_o,
        float* __restrict__ dsum_o, float* __restrict__ S,
        const float* __restrict__ w_re, const float* __restrict__ w_im,
        __hip_bfloat16* __restrict__ E_t, __hip_bfloat16* __restrict__ wfrag,
        __hip_bfloat16* __restrict__ E_inv)
{
    int blk = blockIdx.x;
    if (blk >= NBLK) {
        int idx = (blk - NBLK) * 256 + threadIdx.x;   // 0..65535
        if (idx < 16384) {
            int xx = idx >> 8, dd = idx & 255;
            float v = (xx < 32) ? __cosf(ANG * (float)((xx * dd) & 255))
                                : -__sinf(ANG * (float)(((xx - 32) * dd) & 255));
            E_t[idx] = __float2bfloat16(v);
        } else if (idx < 49152) {
            int f = idx - 16384;
            int nt = f >> 9, l = (f >> 3) & 63, j = f & 7;
            int n = nt * 16 + (l & 15);
            int o = ((l >> 4) & 3) * 8 + j;          // k = o' 0..31
            float v = 0.f;
            if (o < 16) {
                int comp = n >> 9, xm = (n >> 4) & 31, i = n & 15;
                v = comp ? w_im[(i * 16 + o) * 32 + xm] : w_re[(i * 16 + o) * 32 + xm];
            }
            wfrag[f] = __float2bfloat16(v);
        } else {
            int f = idx - 49152;
            int nt = f >> 10, ks = (f >> 9) & 1, l = (f >> 3) & 63, j = f & 7;
            int row = ks * 32 + ((l >> 4) & 3) * 8 + j;
            int col = nt * 16 + (l & 15);
            float v = (row < 32) ? __cosf(ANG * (float)((row * col) & 255))
                                 : -__sinf(ANG * (float)(((row - 32) * col) & 255));
            E_inv[f] = __float2bfloat16(v);
        }
        return;
    }

    __shared__ __align__(16) float xn_s[16 * 260];   // stride 260 -> conflict-free
    __shared__ __align__(16) __bf16 xnb[16 * 256];   // bf16 A-tile [m][d], XOR-swizzled
    __shared__ float dbc_s[16 * 52];
    int tid = threadIdx.x, wave = tid >> 6, lane = tid & 63;
    int grow0 = blk * CL;
    char* xnb_c = (char*)xnb;

    // --- Phase A: LayerNorm, 4 rows per wave ---
#pragma unroll
    for (int rr = 0; rr < 4; rr++) {
        int r = wave * 4 + rr;
        const float* xr = x + (size_t)(grow0 + r) * D_;
        float v[4];
#pragma unroll
        for (int q = 0; q < 4; q++) v[q] = xr[lane + q * 64];
        float sum = v[0] + v[1] + v[2] + v[3];
        float sq  = v[0]*v[0] + v[1]*v[1] + v[2]*v[2] + v[3]*v[3];
#pragma unroll
        for (int off = 32; off; off >>= 1) { sum += __shfl_xor(sum, off); sq += __shfl_xor(sq, off); }
        float mu = sum * (1.f / D_);
        float rstd = rsqrtf(sq * (1.f / D_) - mu * mu + 1e-5f);
#pragma unroll
        for (int q = 0; q < 4; q++) {
            int d = lane + q * 64;
            float xv = (v[q] - mu) * rstd * ln_g[d] + ln_b[d];
            xn_s[r * 260 + d] = xv;
            *(__bf16*)(xnb_c + r * 512 + ((d * 2) ^ ((r & 7) << 4))) = (__bf16)xv;
        }
    }
    __syncthreads();

    // --- Phase B: dbc = xn @ W_xproj^T via MFMA; W-frags inlined ---
    if (wave < 3) {
        int jcol = wave * 16 + (lane & 15);              // 0..47
        const float* wrow = W_xproj + (size_t)jcol * 256 + ((lane >> 4) * 8);
        int mrow = lane & 15;
        f32x4 acc = {0.f, 0.f, 0.f, 0.f};
#pragma unroll
        for (int ks = 0; ks < 8; ks++) {
            bf16x8 af = *(const bf16x8*)(xnb_c + mrow * 512 +
                          ((ks * 64 + ((lane >> 4) * 16)) ^ ((mrow & 7) << 4)));
            f32x4 wa = *(const f32x4*)(wrow + ks * 32);
            f32x4 wb = *(const f32x4*)(wrow + ks * 32 + 4);
            bf16x8 bf;
#pragma unroll
            for (int k = 0; k < 4; k++) { bf[k] = (__bf16)wa[k]; bf[4 + k] = (__bf16)wb[k]; }
            acc = __builtin_amdgcn_mfma_f32_16x16x32_bf16(af, bf, acc, 0, 0, 0);
        }
#pragma unroll
        for (int q = 0; q < 4; q++) {
            int r = (lane >> 4) * 4 + q;
            dbc_s[r * 52 + jcol] = acc[q];
            if (jcol >= 32)      Cc_o[(size_t)(grow0 + r) * 16 + jcol - 32] = acc[q];
            else if (jcol >= 16) Bc_o[(size_t)(grow0 + r) * 16 + jcol - 16] = acc[q];
        }
    }
    __syncthreads();

    // --- Phase C: delta = softplus(dbc[:16] . W_dt[d] + b_dt[d]); pack dxn ---
    int d = tid;
    float wdt[16];
#pragma unroll
    for (int q = 0; q < 4; q++) {
        f32x4 w4 = *(const f32x4*)&W_dt[d * 16 + q * 4];
#pragma unroll
        for (int k = 0; k < 4; k++) wdt[q * 4 + k] = w4[k];
    }
    float bd = b_dt[d];
    float dlt_r[16];
#pragma unroll
    for (int r = 0; r < 16; r++) {
        float din = bd;
#pragma unroll
        for (int k = 0; k < 16; k++) din = fmaf(dbc_s[r * 52 + k], wdt[k], din);
        din = (din > 15.f) ? din : __logf(1.f + __expf(din));   // hw log/exp softplus
        dlt_r[r] = din;
        union { __bf16 h2[2]; unsigned int u; } pk;
        pk.h2[0] = (__bf16)din;
        pk.h2[1] = (__bf16)xn_s[r * 260 + d];
        dxn[(size_t)(grow0 + r) * D_ + d] = pk.u;
    }

    // --- Phase D: local scan over 16 timesteps (uniform-A fast path) ---
    float ar[16];
#pragma unroll
    for (int q = 0; q < 4; q++) {
        f32x4 a4 = *(const f32x4*)&A_log[d * 16 + q * 4];
#pragma unroll
        for (int k = 0; k < 4; k++) ar[q * 4 + k] = -__expf(a4[k]);
    }
    bool uni = true;
#pragma unroll
    for (int n = 1; n < 16; n++) uni = uni && (ar[n] == ar[0]);
    float s[16], dsum = 0.f;
#pragma unroll
    for (int n = 0; n < 16; n++) s[n] = 0.f;
    if (uni) {
        float ar0 = ar[0];
#pragma unroll
        for (int t = 0; t < CL; t++) {
            float dl = dlt_r[t];
            float dx = dl * xn_s[t * 260 + d];
            dsum += dl;
            float e = __expf(dl * ar0);
#pragma unroll
            for (int n = 0; n < 16; n++)
                s[n] = fmaf(e, s[n], dx * dbc_s[t * 52 + 16 + n]);
        }
    } else {
#pragma unroll
        for (int t = 0; t < CL; t++) {
            float dl = dlt_r[t];
            float dx = dl * xn_s[t * 260 + d];
            dsum += dl;
#pragma unroll
            for (int n = 0; n < 16; n++) {
                float e = __expf(dl * ar[n]);
                s[n] = fmaf(e, s[n], dx * dbc_s[t * 52 + 16 + n]);
            }
        }
    }
    dsum_o[(size_t)blk * 256 + d] = dsum;
    size_t o = (size_t)blk * 4096 + d * 16;
#pragma unroll
    for (int q = 0; q < 4; q++) {
        f32x4 sv;
#pragma unroll
        for (int k = 0; k < 4; k++) sv[k] = s[q*4+k];
        *reinterpret_cast<f32x4*>(&S[o + q * 4]) = sv;
    }
}

// ===== kernel 2: inter-chunk scan, 8-way parallel; pv = exp(ar*dsum) =====
__global__ __launch_bounds__(256) void k_scan_par(
        const float* __restrict__ A_log, const float* __restrict__ dsum,
        float* __restrict__ S_H0)
{
    __shared__ float gP[256];
    __shared__ float gS[256];
    int tid = threadIdx.x;
    int g2 = tid >> 5, cl2 = tid & 31;
    int ch = blockIdx.x * 32 + cl2;               // 512*32 = 16384 channels
    int b2 = ch >> 12, dn2 = ch & 4095;
    int dd = dn2 >> 4;
    float arv = -__expf(A_log[dn2]);
    size_t cb = ((size_t)b2 * NC + g2 * 16) * 4096 + dn2;
    size_t db = ((size_t)b2 * NC + g2 * 16) * 256 + dd;
    float pv[16], sv[16];
#pragma unroll
    for (int c = 0; c < 16; c++) {
        pv[c] = __expf(arv * dsum[db + (size_t)c * 256]);
        sv[c] = S_H0[cb + (size_t)c * 4096];
    }
    float pA = 1.f, sA = 0.f;
#pragma unroll
    for (int c = 0; c < 16; c++) { sA = fmaf(pv[c], sA, sv[c]); pA *= pv[c]; }
    gP[g2 * 32 + cl2] = pA;
    gS[g2 * 32 + cl2] = sA;
    __syncthreads();
    float h = 0.f;
    for (int gg = 0; gg < g2; gg++)
        h = fmaf(gP[gg * 32 + cl2], h, gS[gg * 32 + cl2]);
#pragma unroll
    for (int c = 0; c < 16; c++) {
        S_H0[cb + (size_t)c * 4096] = h;          // H0 for chunk (g2*16+c), in place
        h = fmaf(pv[c], h, sv[c]);
    }
}

// ===== kernel 3: re-scan + DFT(MFMA) + wc(MFMA) + g + inverse(MFMA) + epilogue =====
// (byte-identical to the measured-best R11 version)
__global__ __launch_bounds__(256, 2) void k_fused(
        const unsigned int* __restrict__ dxn,
        const float* __restrict__ xin, const float* __restrict__ D_param,
        const float* __restrict__ Bc, const float* __restrict__ Cc,
        const float* __restrict__ A_log, const float* __restrict__ H0,
        float* __restrict__ out,
        const __hip_bfloat16* __restrict__ E_t, const __hip_bfloat16* __restrict__ wfrag,
        const __hip_bfloat16* __restrict__ E_inv)
{
    __shared__ __align__(16) char smem[69760];
    __bf16* hfb  = (__bf16*)(smem + 32768);
    __bf16* gsb  = (__bf16*)(smem + 65536);
    __bf16* ccb  = (__bf16*)(smem + 67712);
    float*  bc_s = (float*)(smem + 68736);

    int tid = threadIdx.x, wave = tid >> 6, lane = tid & 63;
    int wm = wave >> 1, wx = wave & 1;
    int blk = blockIdx.x;
    int grow0 = blk * CL;
    int d = tid;

    // ---- setup ----
    bc_s[tid] = Bc[(size_t)grow0 * 16 + tid];
    {
        float ccv = Cc[(size_t)grow0 * 16 + tid];
        int r = tid >> 4, o = tid & 15;
        ccb[r * 32 + o] = (__bf16)ccv;
        ccb[r * 32 + 16 + o] = (__bf16)0.f;
    }
    unsigned int dxnv[16];
#pragma unroll
    for (int t = 0; t < 16; t++) dxnv[t] = dxn[(size_t)(grow0 + t) * D_ + d];
    float ar[16], h[16];
    {
        size_t ho = (size_t)blk * 4096 + d * 16;
#pragma unroll
        for (int q = 0; q < 4; q++) {
            f32x4 a4 = *(const f32x4*)&A_log[d * 16 + q * 4];
            f32x4 h4 = *(const f32x4*)&H0[ho + q * 4];
#pragma unroll
            for (int k = 0; k < 4; k++) { ar[q*4+k] = -__expf(a4[k]); h[q*4+k] = h4[k]; }
        }
    }
    bool uni = true;
#pragma unroll
    for (int n = 1; n < 16; n++) uni = uni && (ar[n] == ar[0]);
    float ar0 = ar[0];

    // ---- E fragments for this wave's 32 x-columns (VGPR-resident) ----
    bf16x8 bfragAll[2][8];
#pragma unroll
    for (int nt2 = 0; nt2 < 2; nt2++) {
        int xa = wx * 32 + nt2 * 16 + (lane & 15);
#pragma unroll
        for (int ks = 0; ks < 8; ks++)
            bfragAll[nt2][ks] = *(const bf16x8*)(E_t + xa * 256 + ks * 32 + ((lane >> 4) * 8));
    }
    int swz = (lane & 7) << 4;
    f32x4 acc[2][2];
#pragma unroll
    for (int a = 0; a < 2; a++)
#pragma unroll
        for (int b = 0; b < 2; b++) { acc[a][b][0]=0.f; acc[a][b][1]=0.f; acc[a][b][2]=0.f; acc[a][b][3]=0.f; }
    __syncthreads();

    // ---- 4 gulps: scan -> A-tile; DFT MFMA -> hf [r][x][i] ----
#pragma unroll
    for (int g = 0; g < 4; g++) {
        if (uni) {
#pragma unroll
            for (int tl = 0; tl < 4; tl++) {
                unsigned int v = dxnv[g * 4 + tl];
                float dl = __uint_as_float(v << 16);
                float dx = dl * __uint_as_float(v & 0xffff0000u);
                float e = __expf(dl * ar0);
#pragma unroll
                for (int n = 0; n < 16; n++) {
                    h[n] = fmaf(e, h[n], dx * bc_s[(g * 4 + tl) * 16 + n]);
                    int m = tl * 16 + n;
                    *(__bf16*)(smem + m * 512 + ((d * 2) ^ ((m & 7) << 4))) = (__bf16)h[n];
                }
            }
        } else {
#pragma unroll
            for (int tl = 0; tl < 4; tl++) {
                unsigned int v = dxnv[g * 4 + tl];
                float dl = __uint_as_float(v << 16);
                float dx = dl * __uint_as_float(v & 0xffff0000u);
#pragma unroll
                for (int n = 0; n < 16; n++) {
                    float e = __expf(dl * ar[n]);
                    h[n] = fmaf(e, h[n], dx * bc_s[(g * 4 + tl) * 16 + n]);
                    int m = tl * 16 + n;
                    *(__bf16*)(smem + m * 512 + ((d * 2) ^ ((m & 7) << 4))) = (__bf16)h[n];
                }
            }
        }
        __syncthreads();
        // DFT MFMA: wave computes rows (tl = wm*2 + tl2), x-cols wx*32..+31
#pragma unroll
        for (int ks = 0; ks < 8; ks++) {
#pragma unroll
            for (int tl2 = 0; tl2 < 2; tl2++) {
                int m = (wm * 2 + tl2) * 16 + (lane & 15);
                bf16x8 af = *(const bf16x8*)(smem + m * 512 + ((ks * 64 + ((lane >> 4) * 16)) ^ swz));
#pragma unroll
                for (int nt2 = 0; nt2 < 2; nt2++)
                    acc[tl2][nt2] = __builtin_amdgcn_mfma_f32_16x16x32_bf16(af, bfragAll[nt2][ks], acc[tl2][nt2], 0, 0, 0);
            }
        }
        // hf store (vectorized b64: 4 consecutive i) + acc reset
#pragma unroll
        for (int tl2 = 0; tl2 < 2; tl2++) {
            int r = g * 4 + wm * 2 + tl2;
#pragma unroll
            for (int nt2 = 0; nt2 < 2; nt2++) {
                int xcol = wx * 32 + nt2 * 16 + (lane & 15);
                bf16x4 pk;
#pragma unroll
                for (int k = 0; k < 4; k++) { pk[k] = (__bf16)acc[tl2][nt2][k]; acc[tl2][nt2][k] = 0.f; }
                *(bf16x4*)(&hfb[r * 1024 + xcol * 16 + (lane >> 4) * 4]) = pk;
            }
        }
        __syncthreads();
    }

    // ---- prefetch epilogue inputs (hide HBM latency under wc+g) ----
    float xpf[4][4], xnpf[4][4], dpf[4];
#pragma unroll
    for (int ntl = 0; ntl < 4; ntl++) {
        int dcol = (wave * 4 + ntl) * 16 + (lane & 15);
        dpf[ntl] = D_param[dcol];
#pragma unroll
        for (int q = 0; q < 4; q++) {
            int r = (lane >> 4) * 4 + q;
            size_t go = (size_t)(grow0 + r) * D_ + dcol;
            xpf[ntl][q] = xin[go];
            xnpf[ntl][q] = __uint_as_float(dxn[go] & 0xffff0000u);
        }
    }

    // ---- wc = Cc @ w via MFMA (M=16 r, K=32 o', N=1024), into dead A-tile region ----
    {
        bf16x8 ccf = *(const bf16x8*)((char*)ccb + (lane & 15) * 64 + ((lane >> 4) * 16));
#pragma unroll
        for (int ntl = 0; ntl < 16; ntl++) {
            int nt = wave * 16 + ntl;
            f32x4 a = {0.f, 0.f, 0.f, 0.f};
            bf16x8 wf = *(const bf16x8*)(wfrag + (nt * 64 + lane) * 8);
            a = __builtin_amdgcn_mfma_f32_16x16x32_bf16(ccf, wf, a, 0, 0, 0);
            int col = nt * 16 + (lane & 15);
#pragma unroll
            for (int q = 0; q < 4; q++) {
                int r = (lane >> 4) * 4 + q;
                *(__bf16*)(smem + r * 2048 + col * 2) = (__bf16)a[q];
            }
        }
    }
    __syncthreads();

    // ---- g[r,x] = sum_i hf[r,x,i] * wc[r,x,i] (complex); thread = (r, 2 x's) ----
    {
        __bf16* wcb = (__bf16*)smem;
        int r = tid >> 4, x2 = tid & 15;
#pragma unroll
        for (int xh = 0; xh < 2; xh++) {
            int xs = xh * 16 + x2;
            bf16x8 hra = *(const bf16x8*)(&hfb[r * 1024 + xs * 16]);
            bf16x8 hrb = *(const bf16x8*)(&hfb[r * 1024 + xs * 16 + 8]);
            bf16x8 hia = *(const bf16x8*)(&hfb[r * 1024 + (xs + 32) * 16]);
            bf16x8 hib = *(const bf16x8*)(&hfb[r * 1024 + (xs + 32) * 16 + 8]);
            bf16x8 wra = *(const bf16x8*)(&wcb[r * 1024 + xs * 16]);
            bf16x8 wrb = *(const bf16x8*)(&wcb[r * 1024 + xs * 16 + 8]);
            bf16x8 wia = *(const bf16x8*)(&wcb[r * 1024 + 512 + xs * 16]);
            bf16x8 wib = *(const bf16x8*)(&wcb[r * 1024 + 512 + xs * 16 + 8]);
            float gre = 0.f, gim = 0.f;
#pragma unroll
            for (int k = 0; k < 8; k++) {
                float hr = (float)hra[k], hi = (float)hia[k];
                float wr = (float)wra[k], wi = (float)wia[k];
                gre = fmaf(hr, wr, gre); gre = fmaf(-hi, wi, gre);
                gim = fmaf(hr, wi, gim); gim = fmaf(hi, wr, gim);
                float hr2 = (float)hrb[k], hi2 = (float)hib[k];
                float wr2 = (float)wrb[k], wi2 = (float)wib[k];
                gre = fmaf(hr2, wr2, gre); gre = fmaf(-hi2, wi2, gre);
                gim = fmaf(hr2, wi2, gim); gim = fmaf(hi2, wr2, gim);
            }
            float sc = xs ? 2.f : 1.f;
            gsb[r * 68 + xs]      = (__bf16)(gre * sc);
            gsb[r * 68 + 32 + xs] = (__bf16)(gim * sc);
        }
    }
    __syncthreads();

    // ---- inverse DFT via MFMA (M=16 r, K=64, N=256 d') + epilogue ----
    {
        bf16x8 ga0 = *(const bf16x8*)((char*)gsb + (lane & 15) * 136 + ((lane >> 4) * 16));
        bf16x8 ga1 = *(const bf16x8*)((char*)gsb + (lane & 15) * 136 + 64 + ((lane >> 4) * 16));
#pragma unroll
        for (int ntl = 0; ntl < 4; ntl++) {
            int nt = wave * 4 + ntl;
            f32x4 a = {0.f, 0.f, 0.f, 0.f};
            a = __builtin_amdgcn_mfma_f32_16x16x32_bf16(
                    ga0, *(const bf16x8*)(E_inv + ((nt * 2 + 0) * 64 + lane) * 8), a, 0, 0, 0);
            a = __builtin_amdgcn_mfma_f32_16x16x32_bf16(
                    ga1, *(const bf16x8*)(E_inv + ((nt * 2 + 1) * 64 + lane) * 8), a, 0, 0, 0);
            int dcol = nt * 16 + (lane & 15);
#pragma unroll
            for (int q = 0; q < 4; q++) {
                int r = (lane >> 4) * 4 + q;
                size_t go = (size_t)(grow0 + r) * D_ + dcol;
                out[go] = xpf[ntl][q] + dpf[ntl] * xnpf[ntl][q] + a[q] * (1.f / 256.f);
            }
        }
    }
}

// ===== launch =====
extern "C" void kernel_launch(void* const* d_in, const int* in_sizes, int n_in,
                              void* d_out, int out_size, void* d_ws, size_t ws_size,
                              hipStream_t stream)
{
    const float* x       = (const float*)d_in[0];
    const float* ln_g    = (const float*)d_in[1];
    const float* ln_b    = (const float*)d_in[2];
    const float* W_xproj = (const float*)d_in[3];
    const float* W_dt    = (const float*)d_in[4];
    const float* b_dt    = (const float*)d_in[5];
    const float* A_log   = (const float*)d_in[6];
    const float* D_param = (const float*)d_in[7];
    const float* w_re    = (const float*)d_in[8];
    const float* w_im    = (const float*)d_in[9];

    float* ws    = (float*)d_ws;
    float* S_H0  = ws;                               // 2M floats (S, then H0 in place)
    unsigned int* dxn = (unsigned int*)(S_H0 + 2097152); // 2M u32 (bf16 dlt | bf16 xn)
    float* Bc    = (float*)(dxn + 2097152);          // 131072
    float* Cc    = Bc + 131072;                      // 131072
    float* dsum  = Cc + 131072;                      // 131072
    __hip_bfloat16* tab = (__hip_bfloat16*)(dsum + 131072);
    __hip_bfloat16* E_t   = tab;                     // 16384 bf16
    __hip_bfloat16* wfrag = tab + 16384;             // 32768
    __hip_bfloat16* E_inv = tab + 49152;             // 16384
    float* out = (float*)d_out;

    hipLaunchKernelGGL(k_lnscan, dim3(NBLK + 256), dim3(256), 0, stream,
                       x, ln_g, ln_b, W_xproj, W_dt, b_dt, A_log,
                       dxn, Bc, Cc, dsum, S_H0, w_re, w_im, E_t, wfrag, E_inv);
    hipLaunchKernelGGL(k_scan_par, dim3(NBLK), dim3(256), 0, stream, A_log, dsum, S_H0);
    hipLaunchKernelGGL(k_fused, dim3(NBLK), dim3(256), 0, stream,
                       dxn, x, D_param, Bc, Cc, A_log, S_H0, out, E_t, wfrag, E_inv);
}